// Round 3
// baseline (73.514 us; speedup 1.0000x reference)
//
#include <hip/hip_runtime.h>

// Chamfer distance, fp32, A,B = [4][8192][3].
// prep:   tuples (bx,by,bz,b2) for both directions into ws + 0xFF row-min init.
// min:    rows in VGPRs (m2x=-2ax,...), columns via wave-uniform SCALAR loads
//         (SMEM pipe, zero VALU cost). v = fma(m2x,bx,fma(m2y,by,fma(m2z,bz,b2))),
//         acc = min3(acc, v0, v1). Cross-block combine: uint atomicMin (vals >= 0).
// reduce: one 1024-thread block, sum sqrt(rowmin), write out[0]. No atomics/memsets.

constexpr int NB   = 4;
constexpr int NPTS = 8192;
constexpr int R    = 8;                        // rows per lane
constexpr int MSLICE = 256;                    // cols per block (shared by all waves)
constexpr int ROWS_PER_BLOCK = 4 * 64 * R;     // 2048
constexpr int ROWBLKS = NPTS / ROWS_PER_BLOCK; // 4
constexpr int MBLKS   = NPTS / MSLICE;         // 32
// grid = 2 * NB * ROWBLKS * MBLKS = 1024 blocks

__global__ __launch_bounds__(256)
void chamfer_prep_kernel(const float* __restrict__ A,
                         const float* __restrict__ B,
                         unsigned int* __restrict__ ws_min,
                         float4* __restrict__ tups) {
    int idx   = blockIdx.x * 256 + threadIdx.x;   // 0 .. 65535
    int col   = idx & (NPTS - 1);
    int batch = (idx >> 13) & (NB - 1);
    int dir   = idx >> 15;
    const float* src = (dir == 0 ? B : A) + (batch * NPTS + col) * 3;
    float x = src[0], y = src[1], z = src[2];
    tups[idx] = make_float4(x, y, z, x * x + y * y + z * z);
    ws_min[idx] = 0xFFFFFFFFu;
}

__global__ __launch_bounds__(256, 4)
void chamfer_min_kernel(const float* __restrict__ A,
                        const float* __restrict__ B,
                        const float4* __restrict__ tups,
                        unsigned int* __restrict__ ws_min) {
    int bid = blockIdx.x;
    int dir    = bid & 1;             bid >>= 1;
    int mblk   = bid & (MBLKS - 1);   bid >>= 5;
    int rowblk = bid & (ROWBLKS - 1); bid >>= 2;
    int batch  = bid;

    const float* rows = (dir == 0 ? A : B) + batch * NPTS * 3;
    // Column tuple pointer: pure function of blockIdx -> wave-uniform -> s_load.
    const float4* tw = tups + (dir * NB + batch) * NPTS + mblk * MSLICE;
    unsigned int* out_min = ws_min + (dir * NB + batch) * NPTS;

    int lane = threadIdx.x & 63;
    int wave = threadIdx.x >> 6;
    int rowbase = rowblk * ROWS_PER_BLOCK + wave * (64 * R);

    float m2x[R], m2y[R], m2z[R], acc[R];
    #pragma unroll
    for (int r = 0; r < R; ++r) {
        int row = rowbase + r * 64 + lane;
        m2x[r] = -2.0f * rows[row * 3 + 0];
        m2y[r] = -2.0f * rows[row * 3 + 1];
        m2z[r] = -2.0f * rows[row * 3 + 2];
        acc[r] = 3.0e38f;
    }

    #pragma unroll 4
    for (int i = 0; i < MSLICE; i += 2) {
        float4 t0 = tw[i];
        float4 t1 = tw[i + 1];
        #pragma unroll
        for (int r = 0; r < R; ++r) {
            float v0 = fmaf(m2x[r], t0.x, fmaf(m2y[r], t0.y, fmaf(m2z[r], t0.z, t0.w)));
            float v1 = fmaf(m2x[r], t1.x, fmaf(m2y[r], t1.y, fmaf(m2z[r], t1.z, t1.w)));
            acc[r] = fminf(acc[r], fminf(v0, v1));   // -> v_min3_f32
        }
    }

    #pragma unroll
    for (int r = 0; r < R; ++r) {
        // a2 = x^2+y^2+z^2 = 0.25*((-2x)^2 + (-2y)^2 + (-2z)^2)
        float a2 = 0.25f * fmaf(m2x[r], m2x[r], fmaf(m2y[r], m2y[r], m2z[r] * m2z[r]));
        float v = fmaxf(a2 + acc[r], 0.0f);   // >= 0: uint order == float order
        atomicMin(&out_min[rowbase + r * 64 + lane], __float_as_uint(v));
    }
}

__global__ __launch_bounds__(1024)
void chamfer_reduce_kernel(const unsigned int* __restrict__ ws_min,
                           float* __restrict__ out) {
    constexpr float SCALE = 1.0f / (NB * NPTS * 12.8f);
    const uint4* p = reinterpret_cast<const uint4*>(ws_min);  // 16384 entries
    float s = 0.0f;
    #pragma unroll
    for (int k = 0; k < 16; ++k) {
        uint4 v = p[threadIdx.x + k * 1024];
        s += sqrtf(__uint_as_float(v.x)) + sqrtf(__uint_as_float(v.y))
           + sqrtf(__uint_as_float(v.z)) + sqrtf(__uint_as_float(v.w));
    }
    #pragma unroll
    for (int off = 32; off >= 1; off >>= 1)
        s += __shfl_down(s, off, 64);
    __shared__ float red[16];
    if ((threadIdx.x & 63) == 0) red[threadIdx.x >> 6] = s;
    __syncthreads();
    if (threadIdx.x == 0) {
        float tot = 0.0f;
        #pragma unroll
        for (int w = 0; w < 16; ++w) tot += red[w];
        out[0] = tot * SCALE;
    }
}

extern "C" void kernel_launch(void* const* d_in, const int* in_sizes, int n_in,
                              void* d_out, int out_size, void* d_ws, size_t ws_size,
                              hipStream_t stream) {
    const float* A = (const float*)d_in[0];
    const float* B = (const float*)d_in[1];
    float* out = (float*)d_out;
    unsigned int* wsm = (unsigned int*)d_ws;                       // 64K uints = 256 KB
    float4* tups = (float4*)((char*)d_ws + 256 * 1024);            // 64K float4 = 1 MB

    chamfer_prep_kernel<<<2 * NB * NPTS / 256, 256, 0, stream>>>(A, B, wsm, tups);
    chamfer_min_kernel<<<2 * NB * ROWBLKS * MBLKS, 256, 0, stream>>>(A, B, tups, wsm);
    chamfer_reduce_kernel<<<1, 1024, 0, stream>>>(wsm, out);
}